// Round 2
// 3727.978 us; speedup vs baseline: 1.4103x; 1.4103x over previous
//
#include <hip/hip_runtime.h>

#define T_STEPS 1024
#define BATCH   128
#define IDIM    256
#define HDIM    512
#define BH      (BATCH * HDIM)      // 65536
#define TBH     (T_STEPS * BH)      // 67108864

using short8  = __attribute__((ext_vector_type(8))) short;
using floatx4 = __attribute__((ext_vector_type(4))) float;

// ---------- bf16 helpers (RNE, finite inputs only) ----------
__device__ __forceinline__ unsigned short f2bf(float f) {
  unsigned u = __builtin_bit_cast(unsigned, f);
  u += 0x7FFFu + ((u >> 16) & 1u);
  return (unsigned short)(u >> 16);
}
__device__ __forceinline__ float bf2f(unsigned short h) {
  unsigned u = ((unsigned)h) << 16;
  return __builtin_bit_cast(float, u);
}
__device__ __forceinline__ float fast_tanh(float x) {
  // tanh(x) = 1 - 2/(e^{2x}+1); exp->inf / ->0 limits give +/-1 correctly
  float e = __expf(2.0f * x);
  return 1.0f - 2.0f * __builtin_amdgcn_rcpf(e + 1.0f);
}

// Convert 16 consecutive fp32 -> bf16 hi/lo planes, vector-store to LDS.
__device__ __forceinline__ void stage16(const float4* __restrict__ p,
                                        unsigned short* dhi, unsigned short* dlo) {
  short8 h0{}, h1{}, l0{}, l1{};
#pragma unroll
  for (int v = 0; v < 4; v++) {
    float4 fv = p[v];
    float fs[4] = {fv.x, fv.y, fv.z, fv.w};
#pragma unroll
    for (int e = 0; e < 4; e++) {
      int idx = v * 4 + e;
      unsigned short hh = f2bf(fs[e]);
      unsigned short ll = f2bf(fs[e] - bf2f(hh));
      if (idx < 8) { h0[idx] = (short)hh; l0[idx] = (short)ll; }
      else         { h1[idx - 8] = (short)hh; l1[idx - 8] = (short)ll; }
    }
  }
  *(short8*)(dhi)     = h0;
  *(short8*)(dhi + 8) = h1;
  *(short8*)(dlo)     = l0;
  *(short8*)(dlo + 8) = l1;
}

// ================= Kernel A: xw = x @ Wi^T  (written into d_out[0..TBH)) ==========
// (unchanged; ~430 us, secondary to the scan)
__global__ __launch_bounds__(256, 2) void xw_gemm(const float* __restrict__ x,
                                                  const float* __restrict__ Wi,
                                                  float* __restrict__ out) {
  __shared__ unsigned short Ahi[128 * 40], Alo[128 * 40];
  __shared__ unsigned short Bhi[128 * 40], Blo[128 * 40];
  const int bx   = blockIdx.x;
  const int m0   = (bx >> 2) * 128;
  const int n0   = (bx & 3) * 128;
  const int tid  = threadIdx.x;
  const int lane = tid & 63;
  const int wave = tid >> 6;
  const int q    = lane >> 4;
  const int ml   = lane & 15;
  const int wm   = (wave >> 1) * 64;
  const int wn   = (wave & 1) * 64;
  const int srow = tid & 127;   // staging row (both tiles are 128 x 32)
  const int skh  = tid >> 7;    // staging k-half (0/1), 16 floats each

  floatx4 acc[4][4];
#pragma unroll
  for (int i = 0; i < 4; i++)
#pragma unroll
    for (int j = 0; j < 4; j++)
      acc[i][j] = floatx4{0.f, 0.f, 0.f, 0.f};

  for (int kb = 0; kb < 8; kb++) {
    stage16((const float4*)(x  + (size_t)(m0 + srow) * IDIM + kb * 32 + skh * 16),
            &Ahi[srow * 40 + skh * 16], &Alo[srow * 40 + skh * 16]);
    stage16((const float4*)(Wi + (size_t)(n0 + srow) * IDIM + kb * 32 + skh * 16),
            &Bhi[srow * 40 + skh * 16], &Blo[srow * 40 + skh * 16]);
    __syncthreads();

    short8 ah[4], al[4], bh[4], bl[4];
#pragma unroll
    for (int f = 0; f < 4; f++) {
      ah[f] = *(const short8*)&Ahi[(wm + f * 16 + ml) * 40 + q * 8];
      al[f] = *(const short8*)&Alo[(wm + f * 16 + ml) * 40 + q * 8];
      bh[f] = *(const short8*)&Bhi[(wn + f * 16 + ml) * 40 + q * 8];
      bl[f] = *(const short8*)&Blo[(wn + f * 16 + ml) * 40 + q * 8];
    }
#pragma unroll
    for (int mf = 0; mf < 4; mf++)
#pragma unroll
      for (int nf = 0; nf < 4; nf++) {
        acc[mf][nf] = __builtin_amdgcn_mfma_f32_16x16x32_bf16(ah[mf], bh[nf], acc[mf][nf], 0, 0, 0);
        acc[mf][nf] = __builtin_amdgcn_mfma_f32_16x16x32_bf16(ah[mf], bl[nf], acc[mf][nf], 0, 0, 0);
        acc[mf][nf] = __builtin_amdgcn_mfma_f32_16x16x32_bf16(al[mf], bh[nf], acc[mf][nf], 0, 0, 0);
      }
    __syncthreads();
  }

#pragma unroll
  for (int mf = 0; mf < 4; mf++)
#pragma unroll
    for (int nf = 0; nf < 4; nf++)
#pragma unroll
      for (int r = 0; r < 4; r++)
        out[(size_t)(m0 + wm + mf * 16 + q * 4 + r) * HDIM + (n0 + wn + nf * 16 + ml)] =
            acc[mf][nf][r];
}

// ================= Kernel B: recurrence h_t = tanh(xw_t + h_{t-1} Wh^T) ==========
// 32 blocks = 8 batch-groups (16 rows) x 4 j-groups (128 cols). Wh slice in VGPRs.
//
// Sync protocol (V4):
//  - h stores: RELAXED agent-scope atomic stores (bypass L1; release wbl2 in the
//    flag fetch_add still orders them for cross-XCD placements).
//  - flag: release fetch_add (unchanged).
//  - poll: HYBRID spin — relaxed polls with an ACQUIRE poll every 4th iteration.
//    V3's pure-relaxed spin could deadlock: a relaxed agent load may be served
//    from a stale clean line in the local XCD L2 forever (nothing invalidates it;
//    the one fence sat after loop exit). The periodic acquire emits buffer_inv ->
//    guaranteed progress under ANY block->XCD placement, while still ~4x fewer
//    invalidates on the serial chain than acquire-per-poll (round-0 baseline).
//  - own h-slice forwarded registers->LDS at end of step; staging covers only the
//    3 partner slices (24 KB, 384 threads). No block ever global-reads an address
//    it previously wrote (no L1-staleness window).
// Arithmetic is bit-identical to round-0 (same 3-term split-bf16, same
// accumulation order) -> absmax must stay exactly 0.00390625.
__global__ __launch_bounds__(512, 2) void rnn_scan(const float* __restrict__ Wh,
                                                   float* out,
                                                   unsigned* __restrict__ flags) {
  __shared__ unsigned short Hhi[16 * 520], Hlo[16 * 520];
  const int bg     = blockIdx.x & 7;
  const int jg     = blockIdx.x >> 3;
  const int b_base = bg * 16;
  const int j_base = jg * 128;
  const int tid    = threadIdx.x;
  const int lane   = tid & 63;
  const int wave   = tid >> 6;
  const int q      = lane >> 4;
  const int ml     = lane & 15;
  const int col    = j_base + wave * 16 + ml;  // this lane's output column
  const int rowq   = b_base + q * 4;           // first of this lane's 4 D-rows
  const int lrow   = q * 4;                    // LDS-local row base

  // ---- Load Wh fragments into registers (hi/lo), 16 K-chunks of 32 ----
  short8 bfh[16], bfl[16];
#pragma unroll
  for (int c = 0; c < 16; c++) {
    const float4* p = (const float4*)(Wh + (size_t)col * HDIM + c * 32 + q * 8);
    float4 u = p[0], v = p[1];
    float fs[8] = {u.x, u.y, u.z, u.w, v.x, v.y, v.z, v.w};
    short8 h{}, l{};
#pragma unroll
    for (int e = 0; e < 8; e++) {
      unsigned short hh = f2bf(fs[e]);
      h[e] = (short)hh;
      l[e] = (short)f2bf(fs[e] - bf2f(hh));
    }
    bfh[c] = h;
    bfl[c] = l;
  }

  unsigned* const myflags = flags + bg * T_STEPS;

  // ---- t = 0: h_0 = tanh(xw_0) ----
  {
    float hv[4];
#pragma unroll
    for (int r = 0; r < 4; r++) {
      size_t idx = (size_t)(rowq + r) * HDIM + col;
      hv[r] = fast_tanh(out[idx]);
      __hip_atomic_store(&out[idx], hv[r], __ATOMIC_RELAXED, __HIP_MEMORY_SCOPE_AGENT);
    }
    // own-slice h_0 -> LDS from registers (for step 1's A-tile)
#pragma unroll
    for (int r = 0; r < 4; r++) {
      unsigned short hh = f2bf(hv[r]);
      Hhi[(lrow + r) * 520 + col] = hh;
      Hlo[(lrow + r) * 520 + col] = f2bf(hv[r] - bf2f(hh));
    }
    __syncthreads();  // vmcnt(0) drain -> stores acked before flag release
    if (tid == 0)
      __hip_atomic_fetch_add(&myflags[0], 1u,
                             __ATOMIC_RELEASE, __HIP_MEMORY_SCOPE_AGENT);
  }

  for (int t = 1; t < T_STEPS; t++) {
    float* ot         = out + (size_t)t * BH;
    const float* otm1 = out + (size_t)(t - 1) * BH;

    // Prefetch own xw slice (out[t] is only ever written by THIS block) — the
    // loads overlap the spin below.
    float xwv[4];
#pragma unroll
    for (int r = 0; r < 4; r++) xwv[r] = ot[(size_t)(rowq + r) * HDIM + col];

    // Wait for all 4 j-blocks of this batch group to finish step t-1.
    if (tid == 0) {
      int k = 0;
      for (;;) {
        unsigned v = __hip_atomic_load(&myflags[t - 1],
                                       __ATOMIC_RELAXED, __HIP_MEMORY_SCOPE_AGENT);
        if (v >= 4u) break;
        if ((k++ & 3) == 3) {
          // periodic acquire: buffer_inv -> guaranteed progress (no stale-L2 spin)
          v = __hip_atomic_load(&myflags[t - 1],
                                __ATOMIC_ACQUIRE, __HIP_MEMORY_SCOPE_AGENT);
          if (v >= 4u) break;
        }
        __builtin_amdgcn_s_sleep(1);
      }
      __builtin_amdgcn_fence(__ATOMIC_ACQUIRE, "agent");
    }
    __syncthreads();  // #1: block observes tid0's acquire

    // Stage the 3 PARTNER slices of h_{t-1} into LDS as bf16 hi/lo.
    // (own slice was written from registers at the end of step t-1)
    if (tid < 384) {
      const int s   = tid >> 7;                   // partner index 0..2
      const int pc  = ((jg + 1 + s) & 3) * 128;   // partner col base
      const int row = (tid >> 3) & 15;            // 0..15
      const int k0  = (tid & 7) * 16;             // 0..112, 16 floats
      stage16((const float4*)(otm1 + (size_t)(b_base + row) * HDIM + pc + k0),
              &Hhi[row * 520 + pc + k0], &Hlo[row * 520 + pc + k0]);
    }
    __syncthreads();  // #2: LDS A-tile complete

    floatx4 acc = {xwv[0], xwv[1], xwv[2], xwv[3]};
#pragma unroll
    for (int c = 0; c < 16; c++) {
      short8 ahi = *(const short8*)&Hhi[ml * 520 + c * 32 + q * 8];
      short8 alo = *(const short8*)&Hlo[ml * 520 + c * 32 + q * 8];
      acc = __builtin_amdgcn_mfma_f32_16x16x32_bf16(ahi, bfh[c], acc, 0, 0, 0);
      acc = __builtin_amdgcn_mfma_f32_16x16x32_bf16(ahi, bfl[c], acc, 0, 0, 0);
      acc = __builtin_amdgcn_mfma_f32_16x16x32_bf16(alo, bfh[c], acc, 0, 0, 0);
    }

    float hv[4];
#pragma unroll
    for (int r = 0; r < 4; r++) {
      hv[r] = fast_tanh(acc[r]);
      __hip_atomic_store(&ot[(size_t)(rowq + r) * HDIM + col], hv[r],
                         __ATOMIC_RELAXED, __HIP_MEMORY_SCOPE_AGENT);
      if (t == T_STEPS - 1)
        out[(size_t)TBH + (size_t)(rowq + r) * HDIM + col] = hv[r];  // h_final tail
    }
    __syncthreads();  // #3: all waves' stores drained; all LDS reads of this
                      //     step's tile are done
    if (tid == 0)
      __hip_atomic_fetch_add(&myflags[t], 1u,
                             __ATOMIC_RELEASE, __HIP_MEMORY_SCOPE_AGENT);

    // own-slice h_t -> LDS from registers for step t+1 (safe: reads done at #3;
    // ds_writes drain at the next __syncthreads before any wave reads them)
#pragma unroll
    for (int r = 0; r < 4; r++) {
      unsigned short hh = f2bf(hv[r]);
      Hhi[(lrow + r) * 520 + col] = hh;
      Hlo[(lrow + r) * 520 + col] = f2bf(hv[r] - bf2f(hh));
    }
  }
}

extern "C" void kernel_launch(void* const* d_in, const int* in_sizes, int n_in,
                              void* d_out, int out_size, void* d_ws, size_t ws_size,
                              hipStream_t stream) {
  const float* x  = (const float*)d_in[0];   // [T,B,I]
  const float* Wi = (const float*)d_in[1];   // [H,I]
  const float* Wh = (const float*)d_in[2];   // [H,H]
  float* out      = (float*)d_out;           // [T,B,H] ++ [B,H]
  unsigned* flags = (unsigned*)d_ws;         // 8 groups x 1024 steps

  hipMemsetAsync(d_ws, 0, 8 * T_STEPS * sizeof(unsigned), stream);

  // xw -> d_out[0..TBH)
  xw_gemm<<<dim3((131072 / 128) * (HDIM / 128)), dim3(256), 0, stream>>>(x, Wi, out);

  // sequential scan, in-place over d_out
  rnn_scan<<<dim3(32), dim3(512), 0, stream>>>(Wh, out, flags);
}